// Round 1
// baseline (4669.970 us; speedup 1.0000x reference)
//
#include <hip/hip_runtime.h>
#include <math.h>

#define NN 100000
#define EE 3200000
#define FIN 512
#define HID 256
#define CLS 64
#define KST 20

// ---------------- CSR build ----------------

__global__ void zero_kernel(int* __restrict__ degcnt, int* __restrict__ cursor) {
    int i = blockIdx.x * 256 + threadIdx.x;
    if (i < NN) { degcnt[i] = 0; cursor[i] = 0; }
}

__global__ void count_kernel(const int* __restrict__ edst, int* __restrict__ degcnt) {
    int e = blockIdx.x * 256 + threadIdx.x;
    if (e < EE) atomicAdd(&degcnt[edst[e]], 1);
}

__global__ __launch_bounds__(1024) void scan1_kernel(const int* __restrict__ degcnt,
                                                     int* __restrict__ tmp,
                                                     int* __restrict__ bsum) {
    __shared__ int s[1024];
    int t = threadIdx.x;
    int i = blockIdx.x * 1024 + t;
    int v = (i < NN) ? degcnt[i] : 0;
    s[t] = v;
    __syncthreads();
    for (int off = 1; off < 1024; off <<= 1) {
        int xv = (t >= off) ? s[t - off] : 0;
        __syncthreads();
        s[t] += xv;
        __syncthreads();
    }
    if (i < NN) tmp[i] = s[t] - v;              // exclusive scan (local)
    if (t == 1023) bsum[blockIdx.x] = s[1023];  // block total
}

__global__ void scan2_kernel(const int* __restrict__ bsum, int* __restrict__ boff, int nb) {
    if (blockIdx.x == 0 && threadIdx.x == 0) {
        int run = 0;
        for (int b = 0; b < nb; ++b) { boff[b] = run; run += bsum[b]; }
    }
}

__global__ void finalize_kernel(const int* __restrict__ tmp, const int* __restrict__ boff,
                                const int* __restrict__ degcnt,
                                int* __restrict__ rowptr, float* __restrict__ dis) {
    int i = blockIdx.x * 256 + threadIdx.x;
    if (i < NN) {
        rowptr[i] = tmp[i] + boff[i >> 10];
        dis[i] = rsqrtf((float)(degcnt[i] + 1));  // +1 = self loop; deg always > 0
        if (i == 0) rowptr[NN] = EE;
    }
}

__global__ void fill_kernel(const int* __restrict__ esrc, const int* __restrict__ edst,
                            const int* __restrict__ rowptr, int* __restrict__ cursor,
                            int* __restrict__ csrc) {
    int e = blockIdx.x * 256 + threadIdx.x;
    if (e < EE) {
        int d = edst[e];
        int pos = atomicAdd(&cursor[d], 1);
        csrc[rowptr[d] + pos] = esrc[e];
    }
}

// ---------------- fused MLP: h = relu(x@W1+b1)@W2+b2 ----------------
// Block: 256 threads, 32 nodes. Phase 1 stages W1 k-chunks in LDS
// (contiguous ds_read_b128 across the wave = conflict-free), acc[8][4]
// per thread. Phase 2 reuses the LDS buffer for the relu'd T tile.
__global__ __launch_bounds__(256) void mlp_kernel(const float* __restrict__ x,
                                                  const float* __restrict__ W1,
                                                  const float* __restrict__ b1,
                                                  const float* __restrict__ W2,
                                                  const float* __restrict__ b2,
                                                  float* __restrict__ h) {
    __shared__ float Xs[32][36];     // 32 nodes x 32 k (pad to 36 keeps float4 align)
    __shared__ float Buf[32 * 256];  // W1 chunk [32][256], then T [32][256]

    const int t = threadIdx.x;
    const int n0 = blockIdx.x * 32;

    // phase-1 mapping: 64 col-groups of 4, 4 node-groups of 8
    const int j0 = (t & 63) * 4;
    const int i0 = (t >> 6) * 8;
    float acc[8][4];
#pragma unroll
    for (int i = 0; i < 8; ++i)
#pragma unroll
        for (int j = 0; j < 4; ++j) acc[i][j] = 0.f;

    for (int kc = 0; kc < FIN; kc += 32) {
        // stage X chunk: 32x32 floats, one float4 per thread
        {
            int idx = t * 4;
            int r = idx >> 5;
            int c = idx & 31;
            const float4 v = *(const float4*)(x + (size_t)(n0 + r) * FIN + kc + c);
            Xs[r][c + 0] = v.x; Xs[r][c + 1] = v.y; Xs[r][c + 2] = v.z; Xs[r][c + 3] = v.w;
        }
        // stage W1 chunk: 32x256 floats, 8 float4 per thread, coalesced
#pragma unroll
        for (int it = 0; it < 8; ++it) {
            int f4 = t + it * 256;
            int r = f4 >> 6;
            int c4 = (f4 & 63) << 2;
            *(float4*)(Buf + r * 256 + c4) = *(const float4*)(W1 + (size_t)(kc + r) * HID + c4);
        }
        __syncthreads();

#pragma unroll
        for (int k = 0; k < 32; k += 4) {
            float4 w0 = *(const float4*)(Buf + (k + 0) * 256 + j0);
            float4 w1 = *(const float4*)(Buf + (k + 1) * 256 + j0);
            float4 w2 = *(const float4*)(Buf + (k + 2) * 256 + j0);
            float4 w3 = *(const float4*)(Buf + (k + 3) * 256 + j0);
#pragma unroll
            for (int i = 0; i < 8; ++i) {
                const float4 xv = *(const float4*)(&Xs[i0 + i][k]);
                acc[i][0] += xv.x * w0.x + xv.y * w1.x + xv.z * w2.x + xv.w * w3.x;
                acc[i][1] += xv.x * w0.y + xv.y * w1.y + xv.z * w2.y + xv.w * w3.y;
                acc[i][2] += xv.x * w0.z + xv.y * w1.z + xv.z * w2.z + xv.w * w3.z;
                acc[i][3] += xv.x * w0.w + xv.y * w1.w + xv.z * w2.w + xv.w * w3.w;
            }
        }
        __syncthreads();
    }

    // bias + relu, write T tile into Buf
    {
        const float4 bv = *(const float4*)(b1 + j0);
#pragma unroll
        for (int i = 0; i < 8; ++i) {
            float4 tv;
            tv.x = fmaxf(acc[i][0] + bv.x, 0.f);
            tv.y = fmaxf(acc[i][1] + bv.y, 0.f);
            tv.z = fmaxf(acc[i][2] + bv.z, 0.f);
            tv.w = fmaxf(acc[i][3] + bv.w, 0.f);
            *(float4*)(Buf + (i0 + i) * 256 + j0) = tv;
        }
    }
    __syncthreads();

    // phase 2: H[32][64] = T @ W2 + b2
    {
        const int c = t & 63;
        const int i20 = (t >> 6) * 8;
        float acc2[8];
#pragma unroll
        for (int i = 0; i < 8; ++i) acc2[i] = 0.f;

        for (int k = 0; k < HID; k += 4) {
            float w20 = W2[(size_t)(k + 0) * CLS + c];
            float w21 = W2[(size_t)(k + 1) * CLS + c];
            float w22 = W2[(size_t)(k + 2) * CLS + c];
            float w23 = W2[(size_t)(k + 3) * CLS + c];
#pragma unroll
            for (int i = 0; i < 8; ++i) {
                const float4 tv = *(const float4*)(Buf + (i20 + i) * 256 + k);
                acc2[i] += tv.x * w20 + tv.y * w21 + tv.z * w22 + tv.w * w23;
            }
        }
        const float bias2 = b2[c];
#pragma unroll
        for (int i = 0; i < 8; ++i)
            h[(size_t)(n0 + i20 + i) * CLS + c] = acc2[i] + bias2;
    }
}

// ---------------- propagation: zout = 0.9 * dis[d] * (sum_{s in N(d)} z[s]*dis[s] + z[d]*dis[d]) + 0.1*h ----------------
// one wave per node, lane = channel (C = 64 = wavefront)
__global__ __launch_bounds__(256) void prop_kernel(const float* __restrict__ zin,
                                                   const float* __restrict__ h,
                                                   const float* __restrict__ dis,
                                                   const int* __restrict__ rowptr,
                                                   const int* __restrict__ csrc,
                                                   float* __restrict__ zout) {
    int node = (blockIdx.x * 256 + threadIdx.x) >> 6;
    int lane = threadIdx.x & 63;
    if (node >= NN) return;

    const float din = dis[node];
    float acc = zin[(size_t)node * CLS + lane] * din;  // self loop

    int p = rowptr[node];
    const int e = rowptr[node + 1];
    for (; p + 1 < e; p += 2) {
        int s0 = csrc[p];
        int s1 = csrc[p + 1];
        float d0 = dis[s0];
        float d1 = dis[s1];
        acc += zin[(size_t)s0 * CLS + lane] * d0;
        acc += zin[(size_t)s1 * CLS + lane] * d1;
    }
    if (p < e) {
        int s = csrc[p];
        acc += zin[(size_t)s * CLS + lane] * dis[s];
    }

    zout[(size_t)node * CLS + lane] = 0.9f * din * acc + 0.1f * h[(size_t)node * CLS + lane];
}

// ---------------- log_softmax over C=64 ----------------
__global__ void lsm_kernel(const float* __restrict__ z, float* __restrict__ out) {
    int node = (blockIdx.x * 256 + threadIdx.x) >> 6;
    int lane = threadIdx.x & 63;
    if (node >= NN) return;
    float v = z[(size_t)node * CLS + lane];
    float m = v;
#pragma unroll
    for (int o = 32; o; o >>= 1) m = fmaxf(m, __shfl_xor(m, o));
    float ev = __expf(v - m);
    float s = ev;
#pragma unroll
    for (int o = 32; o; o >>= 1) s += __shfl_xor(s, o);
    out[(size_t)node * CLS + lane] = v - m - __logf(s);
}

extern "C" void kernel_launch(void* const* d_in, const int* in_sizes, int n_in,
                              void* d_out, int out_size, void* d_ws, size_t ws_size,
                              hipStream_t stream) {
    const float* x  = (const float*)d_in[0];
    const int*   ei = (const int*)d_in[1];
    const float* W1 = (const float*)d_in[2];
    const float* b1 = (const float*)d_in[3];
    const float* W2 = (const float*)d_in[4];
    const float* b2 = (const float*)d_in[5];
    float* out = (float*)d_out;

    const int* esrc = ei;        // edge_index[0] = message sources
    const int* edst = ei + EE;   // edge_index[1] = aggregation targets

    char* w = (char*)d_ws;
    float* h  = (float*)w;  w += (size_t)NN * CLS * 4;
    float* z0 = (float*)w;  w += (size_t)NN * CLS * 4;
    float* z1 = (float*)w;  w += (size_t)NN * CLS * 4;
    float* dis = (float*)w; w += (size_t)NN * 4;
    int* degcnt = (int*)w;  w += (size_t)NN * 4;
    int* tmp    = (int*)w;  w += (size_t)NN * 4;
    int* rowptr = (int*)w;  w += (size_t)(NN + 1) * 4;
    int* cursor = (int*)w;  w += (size_t)NN * 4;
    int* csrc   = (int*)w;  w += (size_t)EE * 4;
    int* bsum   = (int*)w;  w += 128 * 4;
    int* boff   = (int*)w;  w += 128 * 4;

    const int nbN = (NN + 255) / 256;
    const int nbE = (EE + 255) / 256;
    const int nscan = (NN + 1023) / 1024;  // 98

    zero_kernel<<<nbN, 256, 0, stream>>>(degcnt, cursor);
    count_kernel<<<nbE, 256, 0, stream>>>(edst, degcnt);
    scan1_kernel<<<nscan, 1024, 0, stream>>>(degcnt, tmp, bsum);
    scan2_kernel<<<1, 64, 0, stream>>>(bsum, boff, nscan);
    finalize_kernel<<<nbN, 256, 0, stream>>>(tmp, boff, degcnt, rowptr, dis);
    fill_kernel<<<nbE, 256, 0, stream>>>(esrc, edst, rowptr, cursor, csrc);

    mlp_kernel<<<NN / 32, 256, 0, stream>>>(x, W1, b1, W2, b2, h);

    const float* zin = h;
    float* zout = z0;
    for (int s = 0; s < KST; ++s) {
        prop_kernel<<<(NN * 64) / 256, 256, 0, stream>>>(zin, h, dis, rowptr, csrc, zout);
        if (s == 0) { zin = z0; zout = z1; }
        else { float* tz = (float*)zin; zin = zout; zout = tz; }
    }

    lsm_kernel<<<(NN * 64) / 256, 256, 0, stream>>>(zin, out);
}

// Round 2
// 2626.653 us; speedup vs baseline: 1.7779x; 1.7779x over previous
//
#include <hip/hip_runtime.h>
#include <hip/hip_bf16.h>
#include <math.h>

#define NN 100000
#define EE 3200000
#define FIN 512
#define HID 256
#define CLS 64
#define KST 20

typedef __attribute__((ext_vector_type(8))) short bf16x8;
typedef __attribute__((ext_vector_type(4))) float f32x4;

__device__ __forceinline__ short f2bf(float f) {
    union { __hip_bfloat16 b; short s; } u;
    u.b = __float2bfloat16(f);
    return u.s;
}

// ---------------- CSR build ----------------

__global__ void zero_kernel(int* __restrict__ degcnt, int* __restrict__ cursor) {
    int i = blockIdx.x * 256 + threadIdx.x;
    if (i < NN) { degcnt[i] = 0; cursor[i] = 0; }
}

__global__ void count_kernel(const int* __restrict__ edst, int* __restrict__ degcnt) {
    int e = blockIdx.x * 256 + threadIdx.x;
    if (e < EE) atomicAdd(&degcnt[edst[e]], 1);
}

__global__ __launch_bounds__(1024) void scan1_kernel(const int* __restrict__ degcnt,
                                                     int* __restrict__ tmp,
                                                     int* __restrict__ bsum) {
    __shared__ int s[1024];
    int t = threadIdx.x;
    int i = blockIdx.x * 1024 + t;
    int v = (i < NN) ? degcnt[i] : 0;
    s[t] = v;
    __syncthreads();
    for (int off = 1; off < 1024; off <<= 1) {
        int xv = (t >= off) ? s[t - off] : 0;
        __syncthreads();
        s[t] += xv;
        __syncthreads();
    }
    if (i < NN) tmp[i] = s[t] - v;
    if (t == 1023) bsum[blockIdx.x] = s[1023];
}

__global__ void scan2_kernel(const int* __restrict__ bsum, int* __restrict__ boff, int nb) {
    if (blockIdx.x == 0 && threadIdx.x == 0) {
        int run = 0;
        for (int b = 0; b < nb; ++b) { boff[b] = run; run += bsum[b]; }
    }
}

__global__ void finalize_kernel(const int* __restrict__ tmp, const int* __restrict__ boff,
                                const int* __restrict__ degcnt,
                                int* __restrict__ rowptr, float* __restrict__ dis) {
    int i = blockIdx.x * 256 + threadIdx.x;
    if (i < NN) {
        rowptr[i] = tmp[i] + boff[i >> 10];
        dis[i] = rsqrtf((float)(degcnt[i] + 1));
        if (i == 0) rowptr[NN] = EE;
    }
}

__global__ void fill_kernel(const int* __restrict__ esrc, const int* __restrict__ edst,
                            const int* __restrict__ rowptr, int* __restrict__ cursor,
                            int* __restrict__ csrc) {
    int e = blockIdx.x * 256 + threadIdx.x;
    if (e < EE) {
        int d = edst[e];
        int pos = atomicAdd(&cursor[d], 1);
        csrc[rowptr[d] + pos] = esrc[e];
    }
}

// ---------------- weight prep: transpose + bf16 ----------------

__global__ void w1t_kernel(const float* __restrict__ W1, __hip_bfloat16* __restrict__ W1T) {
    int i = blockIdx.x * 256 + threadIdx.x;     // [HID][FIN]
    if (i < HID * FIN) {
        int c = i >> 9;
        int k = i & (FIN - 1);
        W1T[i] = __float2bfloat16(W1[k * HID + c]);
    }
}

__global__ void w2t_kernel(const float* __restrict__ W2, __hip_bfloat16* __restrict__ W2T) {
    int i = blockIdx.x * 256 + threadIdx.x;     // [CLS][HID]
    if (i < CLS * HID) {
        int c = i >> 8;
        int k = i & (HID - 1);
        W2T[i] = __float2bfloat16(W2[k * CLS + c]);
    }
}

// ---------------- MFMA MLP: hb = relu(x@W1+b1)@W2+b2 (bf16 out), y0 = hb*dis ----------------
// One wave per 64-row tile. GEMM1: A = x rows (f32->bf16 inline), B = W1T (bf16 [256][512]).
// T chunk (64x64) staged in XOR-swizzled LDS; GEMM2 accumulates per chunk over K=256.
__device__ __forceinline__ bf16x8 load_a8(const float* p) {
    const float4 f0 = *(const float4*)p;
    const float4 f1 = *(const float4*)(p + 4);
    bf16x8 r;
    r[0] = f2bf(f0.x); r[1] = f2bf(f0.y); r[2] = f2bf(f0.z); r[3] = f2bf(f0.w);
    r[4] = f2bf(f1.x); r[5] = f2bf(f1.y); r[6] = f2bf(f1.z); r[7] = f2bf(f1.w);
    return r;
}

__global__ __launch_bounds__(64, 2) void mlp_kernel(const float* __restrict__ x,
                                                    const __hip_bfloat16* __restrict__ W1T,
                                                    const float* __restrict__ b1,
                                                    const __hip_bfloat16* __restrict__ W2T,
                                                    const float* __restrict__ b2,
                                                    const float* __restrict__ dis,
                                                    __hip_bfloat16* __restrict__ hb,
                                                    __hip_bfloat16* __restrict__ y0) {
    __shared__ __align__(16) char Tlds[64 * 64 * 2];  // T chunk, XOR-swizzled

    const int lane = threadIdx.x;
    const int r0 = blockIdx.x * 64;
    const int lg = lane >> 4;
    const int li = lane & 15;

    int rowA[4];
#pragma unroll
    for (int mf = 0; mf < 4; ++mf) {
        int r = r0 + mf * 16 + li;
        rowA[mf] = (r < NN) ? r : (NN - 1);
    }

    f32x4 acc2[4][4];
#pragma unroll
    for (int mf = 0; mf < 4; ++mf)
#pragma unroll
        for (int nf = 0; nf < 4; ++nf)
#pragma unroll
            for (int r = 0; r < 4; ++r) acc2[mf][nf][r] = 0.f;

    for (int nc = 0; nc < 4; ++nc) {
        f32x4 acc1[4][4];
#pragma unroll
        for (int mf = 0; mf < 4; ++mf)
#pragma unroll
            for (int nf = 0; nf < 4; ++nf)
#pragma unroll
                for (int r = 0; r < 4; ++r) acc1[mf][nf][r] = 0.f;

        bf16x8 a0[4], b0[4], a1[4], b1v[4];

#define LOADA(dst, ks)                                                              \
        _Pragma("unroll")                                                           \
        for (int mf = 0; mf < 4; ++mf)                                              \
            dst[mf] = load_a8(x + (size_t)rowA[mf] * FIN + (ks) * 32 + lg * 8);
#define LOADB(dst, ks)                                                              \
        _Pragma("unroll")                                                           \
        for (int nf = 0; nf < 4; ++nf)                                              \
            dst[nf] = *(const bf16x8*)(W1T + (size_t)(nc * 64 + nf * 16 + li) * FIN \
                                       + (ks) * 32 + lg * 8);
#define MFMA16(A, B)                                                                \
        _Pragma("unroll")                                                           \
        for (int mf = 0; mf < 4; ++mf)                                              \
            _Pragma("unroll")                                                       \
            for (int nf = 0; nf < 4; ++nf)                                          \
                acc1[mf][nf] = __builtin_amdgcn_mfma_f32_16x16x32_bf16(             \
                    A[mf], B[nf], acc1[mf][nf], 0, 0, 0);

        LOADA(a0, 0); LOADB(b0, 0);
#pragma unroll
        for (int ks = 0; ks < 16; ks += 2) {
            LOADA(a1, ks + 1); LOADB(b1v, ks + 1);
            MFMA16(a0, b0);
            if (ks + 2 < 16) { LOADA(a0, ks + 2); LOADB(b0, ks + 2); }
            MFMA16(a1, b1v);
        }

        // bias + relu -> LDS (bf16, swizzled)
#pragma unroll
        for (int nf = 0; nf < 4; ++nf) {
            const float bv = b1[nc * 64 + nf * 16 + li];
#pragma unroll
            for (int mf = 0; mf < 4; ++mf) {
#pragma unroll
                for (int r = 0; r < 4; ++r) {
                    int row = mf * 16 + lg * 4 + r;
                    int col = nf * 16 + li;
                    float t = fmaxf(acc1[mf][nf][r] + bv, 0.f);
                    int byte = (row * 128 + col * 2) ^ ((row & 7) << 4);
                    *(short*)(Tlds + byte) = f2bf(t);
                }
            }
        }
        __syncthreads();

        // GEMM2 partial: acc2 += T_chunk @ W2T_chunk
#pragma unroll
        for (int ks2 = 0; ks2 < 2; ++ks2) {
            bf16x8 at[4];
#pragma unroll
            for (int mf = 0; mf < 4; ++mf) {
                int row = mf * 16 + li;
                int kk = ks2 * 32 + lg * 8;
                int byte = (row * 128 + kk * 2) ^ ((row & 7) << 4);
                at[mf] = *(const bf16x8*)(Tlds + byte);
            }
#pragma unroll
            for (int nf = 0; nf < 4; ++nf) {
                bf16x8 bw = *(const bf16x8*)(W2T + (size_t)(nf * 16 + li) * HID
                                             + nc * 64 + ks2 * 32 + lg * 8);
#pragma unroll
                for (int mf = 0; mf < 4; ++mf)
                    acc2[mf][nf] = __builtin_amdgcn_mfma_f32_16x16x32_bf16(
                        at[mf], bw, acc2[mf][nf], 0, 0, 0);
            }
        }
        __syncthreads();
    }

    // epilogue: H = acc2 + b2; hb = bf16(H); y0 = bf16(H * dis[row])
    float b2v[4];
#pragma unroll
    for (int nf = 0; nf < 4; ++nf) b2v[nf] = b2[nf * 16 + li];

#pragma unroll
    for (int mf = 0; mf < 4; ++mf) {
#pragma unroll
        for (int r = 0; r < 4; ++r) {
            int row = r0 + mf * 16 + lg * 4 + r;
            if (row < NN) {
                const float dv = dis[row];
#pragma unroll
                for (int nf = 0; nf < 4; ++nf) {
                    float hv = acc2[mf][nf][r] + b2v[nf];
                    size_t o = (size_t)row * CLS + nf * 16 + li;
                    hb[o] = __float2bfloat16(hv);
                    y0[o] = __float2bfloat16(hv * dv);
                }
            }
        }
    }
}

// ---------------- propagation on y = z*dis (bf16) ----------------
// y_new[d] = dis[d] * (0.9*dis[d]*(sum_{s in N(d)} y[s] + y[d]) + 0.1*h[d])
// LAST step emits log_softmax(z) directly.
template <int LAST>
__global__ __launch_bounds__(256) void prop_kernel(const __hip_bfloat16* __restrict__ yin,
                                                   const __hip_bfloat16* __restrict__ hb,
                                                   const float* __restrict__ dis,
                                                   const int* __restrict__ rowptr,
                                                   const int* __restrict__ csrc,
                                                   __hip_bfloat16* __restrict__ yout,
                                                   float* __restrict__ zout) {
    const int node = (blockIdx.x * 256 + threadIdx.x) >> 6;
    const int lane = threadIdx.x & 63;

    float acc = __bfloat162float(yin[(size_t)node * CLS + lane]);  // self loop

    int p = rowptr[node];
    const int e = rowptr[node + 1];
    for (; p + 3 < e; p += 4) {
        int s0 = csrc[p], s1 = csrc[p + 1], s2 = csrc[p + 2], s3 = csrc[p + 3];
        float v0 = __bfloat162float(yin[(size_t)s0 * CLS + lane]);
        float v1 = __bfloat162float(yin[(size_t)s1 * CLS + lane]);
        float v2 = __bfloat162float(yin[(size_t)s2 * CLS + lane]);
        float v3 = __bfloat162float(yin[(size_t)s3 * CLS + lane]);
        acc += v0; acc += v1; acc += v2; acc += v3;
    }
    for (; p < e; ++p)
        acc += __bfloat162float(yin[(size_t)csrc[p] * CLS + lane]);

    const float din = dis[node];
    const float z = 0.9f * din * acc + 0.1f * __bfloat162float(hb[(size_t)node * CLS + lane]);

    if (LAST) {
        float m = z;
#pragma unroll
        for (int o = 32; o; o >>= 1) m = fmaxf(m, __shfl_xor(m, o));
        float ev = __expf(z - m);
        float s = ev;
#pragma unroll
        for (int o = 32; o; o >>= 1) s += __shfl_xor(s, o);
        zout[(size_t)node * CLS + lane] = z - m - __logf(s);
    } else {
        yout[(size_t)node * CLS + lane] = __float2bfloat16(z * din);
    }
}

extern "C" void kernel_launch(void* const* d_in, const int* in_sizes, int n_in,
                              void* d_out, int out_size, void* d_ws, size_t ws_size,
                              hipStream_t stream) {
    const float* x  = (const float*)d_in[0];
    const int*   ei = (const int*)d_in[1];
    const float* W1 = (const float*)d_in[2];
    const float* b1 = (const float*)d_in[3];
    const float* W2 = (const float*)d_in[4];
    const float* b2 = (const float*)d_in[5];
    float* out = (float*)d_out;

    const int* esrc = ei;
    const int* edst = ei + EE;

    char* w = (char*)d_ws;
    auto alloc = [&](size_t bytes) {
        char* p = w;
        w += (bytes + 255) & ~(size_t)255;
        return p;
    };
    __hip_bfloat16* hb  = (__hip_bfloat16*)alloc((size_t)NN * CLS * 2);
    __hip_bfloat16* y0  = (__hip_bfloat16*)alloc((size_t)NN * CLS * 2);
    __hip_bfloat16* y1  = (__hip_bfloat16*)alloc((size_t)NN * CLS * 2);
    __hip_bfloat16* W1T = (__hip_bfloat16*)alloc((size_t)HID * FIN * 2);
    __hip_bfloat16* W2T = (__hip_bfloat16*)alloc((size_t)CLS * HID * 2);
    float* dis   = (float*)alloc((size_t)NN * 4);
    int* degcnt  = (int*)alloc((size_t)NN * 4);
    int* tmp     = (int*)alloc((size_t)NN * 4);
    int* rowptr  = (int*)alloc((size_t)(NN + 1) * 4);
    int* cursor  = (int*)alloc((size_t)NN * 4);
    int* csrc    = (int*)alloc((size_t)EE * 4);
    int* bsum    = (int*)alloc(128 * 4);
    int* boff    = (int*)alloc(128 * 4);

    const int nbN = (NN + 255) / 256;
    const int nbE = (EE + 255) / 256;
    const int nscan = (NN + 1023) / 1024;

    zero_kernel<<<nbN, 256, 0, stream>>>(degcnt, cursor);
    count_kernel<<<nbE, 256, 0, stream>>>(edst, degcnt);
    scan1_kernel<<<nscan, 1024, 0, stream>>>(degcnt, tmp, bsum);
    scan2_kernel<<<1, 64, 0, stream>>>(bsum, boff, nscan);
    finalize_kernel<<<nbN, 256, 0, stream>>>(tmp, boff, degcnt, rowptr, dis);
    fill_kernel<<<nbE, 256, 0, stream>>>(esrc, edst, rowptr, cursor, csrc);

    w1t_kernel<<<(HID * FIN) / 256, 256, 0, stream>>>(W1, W1T);
    w2t_kernel<<<(CLS * HID) / 256, 256, 0, stream>>>(W2, W2T);

    mlp_kernel<<<(NN + 63) / 64, 64, 0, stream>>>(x, W1T, b1, W2T, b2, dis, hb, y0);

    const __hip_bfloat16* yin = y0;
    __hip_bfloat16* yout = y1;
    for (int s = 0; s < KST - 1; ++s) {
        prop_kernel<0><<<(NN * CLS) / 256, 256, 0, stream>>>(yin, hb, dis, rowptr, csrc, yout, nullptr);
        const __hip_bfloat16* t = yin;
        yin = yout;
        yout = (__hip_bfloat16*)t;
    }
    prop_kernel<1><<<(NN * CLS) / 256, 256, 0, stream>>>(yin, hb, dis, rowptr, csrc, nullptr, out);
}

// Round 3
// 1799.561 us; speedup vs baseline: 2.5951x; 1.4596x over previous
//
#include <hip/hip_runtime.h>
#include <hip/hip_bf16.h>
#include <math.h>

#define NN 100000
#define EE 3200000
#define FIN 512
#define HID 256
#define CLS 64
#define KST 20

typedef __attribute__((ext_vector_type(8))) short bf16x8;
typedef __attribute__((ext_vector_type(4))) float f32x4;

__device__ __forceinline__ short f2bf(float f) {
    union { __hip_bfloat16 b; short s; } u;
    u.b = __float2bfloat16(f);
    return u.s;
}
__device__ __forceinline__ float bf2f(__hip_bfloat16 b) { return __bfloat162float(b); }

// ---------------- CSR build ----------------

__global__ void zero_kernel(int* __restrict__ degcnt, int* __restrict__ cursor) {
    int i = blockIdx.x * 256 + threadIdx.x;
    if (i < NN) { degcnt[i] = 0; cursor[i] = 0; }
}

__global__ void count_kernel(const int* __restrict__ edst, int* __restrict__ degcnt) {
    int e = blockIdx.x * 256 + threadIdx.x;
    if (e < EE) atomicAdd(&degcnt[edst[e]], 1);
}

__global__ __launch_bounds__(1024) void scan1_kernel(const int* __restrict__ degcnt,
                                                     int* __restrict__ tmp,
                                                     int* __restrict__ bsum) {
    __shared__ int s[1024];
    int t = threadIdx.x;
    int i = blockIdx.x * 1024 + t;
    int v = (i < NN) ? degcnt[i] : 0;
    s[t] = v;
    __syncthreads();
    for (int off = 1; off < 1024; off <<= 1) {
        int xv = (t >= off) ? s[t - off] : 0;
        __syncthreads();
        s[t] += xv;
        __syncthreads();
    }
    if (i < NN) tmp[i] = s[t] - v;
    if (t == 1023) bsum[blockIdx.x] = s[1023];
}

__global__ void scan2_kernel(const int* __restrict__ bsum, int* __restrict__ boff, int nb) {
    if (blockIdx.x == 0 && threadIdx.x == 0) {
        int run = 0;
        for (int b = 0; b < nb; ++b) { boff[b] = run; run += bsum[b]; }
    }
}

__global__ void finalize_kernel(const int* __restrict__ tmp, const int* __restrict__ boff,
                                const int* __restrict__ degcnt,
                                int* __restrict__ rowptr, float* __restrict__ dis) {
    int i = blockIdx.x * 256 + threadIdx.x;
    if (i < NN) {
        rowptr[i] = tmp[i] + boff[i >> 10];
        dis[i] = rsqrtf((float)(degcnt[i] + 1));
        if (i == 0) rowptr[NN] = EE;
    }
}

__global__ void fill_kernel(const int* __restrict__ esrc, const int* __restrict__ edst,
                            const int* __restrict__ rowptr, int* __restrict__ cursor,
                            int* __restrict__ csrc) {
    int e = blockIdx.x * 256 + threadIdx.x;
    if (e < EE) {
        int d = edst[e];
        int pos = atomicAdd(&cursor[d], 1);
        csrc[rowptr[d] + pos] = esrc[e];
    }
}

// ---------------- weight prep: transpose + bf16 ----------------

__global__ void w1t_kernel(const float* __restrict__ W1, __hip_bfloat16* __restrict__ W1T) {
    int i = blockIdx.x * 256 + threadIdx.x;     // [HID][FIN]
    if (i < HID * FIN) {
        int c = i >> 9;
        int k = i & (FIN - 1);
        W1T[i] = __float2bfloat16(W1[k * HID + c]);
    }
}

__global__ void w2t_kernel(const float* __restrict__ W2, __hip_bfloat16* __restrict__ W2T) {
    int i = blockIdx.x * 256 + threadIdx.x;     // [CLS][HID]
    if (i < CLS * HID) {
        int c = i >> 8;
        int k = i & (HID - 1);
        W2T[i] = __float2bfloat16(W2[k * CLS + c]);
    }
}

// ---------------- MFMA MLP ----------------
// Block = 256 threads (4 waves), 64 rows. x staged once per K-chunk into
// XOR-swizzled bf16 LDS (shared by all waves). Wave w computes T chunk cols
// [w*64,(w+1)*64) (GEMM1), T exchanged via swizzled LDS, then GEMM2 with
// M split across waves (wave w -> output rows [w*16,(w+1)*16)).
__global__ __launch_bounds__(256, 3) void mlp_kernel(const float* __restrict__ x,
                                                     const __hip_bfloat16* __restrict__ W1T,
                                                     const float* __restrict__ b1,
                                                     const __hip_bfloat16* __restrict__ W2T,
                                                     const float* __restrict__ b2,
                                                     const float* __restrict__ dis,
                                                     __hip_bfloat16* __restrict__ hb,
                                                     __hip_bfloat16* __restrict__ y0) {
    __shared__ __align__(16) char Alds[64 * 256];   // 64 rows x 128 k, bf16, swizzled (16 KB)
    __shared__ __align__(16) char Tlds[64 * 512];   // 64 rows x 256 cols, bf16, swizzled (32 KB)

    const int t = threadIdx.x;
    const int w = t >> 6;
    const int lane = t & 63;
    const int lg = lane >> 4;
    const int li = lane & 15;
    const int r0 = blockIdx.x * 64;

    f32x4 acc1[4][4];
#pragma unroll
    for (int mf = 0; mf < 4; ++mf)
#pragma unroll
        for (int nf = 0; nf < 4; ++nf)
#pragma unroll
            for (int r = 0; r < 4; ++r) acc1[mf][nf][r] = 0.f;

    for (int kc = 0; kc < FIN; kc += 128) {
        // stage A chunk: 64 rows x 128 k (f32 -> bf16, swizzled)
#pragma unroll
        for (int i = 0; i < 8; ++i) {
            int f = t + i * 256;          // float4 index (2048 total)
            int row = f >> 5;             // 32 float4 per row
            int c4 = (f & 31) << 2;       // col in floats
            int srcrow = r0 + row; if (srcrow >= NN) srcrow = NN - 1;
            float4 v = *(const float4*)(x + (size_t)srcrow * FIN + kc + c4);
            short4 b;
            b.x = f2bf(v.x); b.y = f2bf(v.y); b.z = f2bf(v.z); b.w = f2bf(v.w);
            int byte = row * 256 + ((c4 * 2) ^ ((row & 7) << 4));
            *(short4*)(Alds + byte) = b;
        }
        __syncthreads();

#pragma unroll
        for (int ks = 0; ks < 4; ++ks) {
            bf16x8 af[4], bfw[4];
#pragma unroll
            for (int mf = 0; mf < 4; ++mf) {
                int row = mf * 16 + li;
                int kb = (ks * 32 + lg * 8) * 2;
                af[mf] = *(const bf16x8*)(Alds + row * 256 + (kb ^ ((row & 7) << 4)));
            }
#pragma unroll
            for (int nf = 0; nf < 4; ++nf)
                bfw[nf] = *(const bf16x8*)(W1T + (size_t)(w * 64 + nf * 16 + li) * FIN
                                           + kc + ks * 32 + lg * 8);
#pragma unroll
            for (int mf = 0; mf < 4; ++mf)
#pragma unroll
                for (int nf = 0; nf < 4; ++nf)
                    acc1[mf][nf] = __builtin_amdgcn_mfma_f32_16x16x32_bf16(
                        af[mf], bfw[nf], acc1[mf][nf], 0, 0, 0);
        }
        __syncthreads();
    }

    // T = relu(acc1 + b1) -> swizzled LDS (wave w owns cols w*64..w*64+63)
#pragma unroll
    for (int nf = 0; nf < 4; ++nf) {
        const float bv = b1[w * 64 + nf * 16 + li];
        const int col = w * 64 + nf * 16 + li;
#pragma unroll
        for (int mf = 0; mf < 4; ++mf) {
#pragma unroll
            for (int r = 0; r < 4; ++r) {
                int row = mf * 16 + lg * 4 + r;
                float tv = fmaxf(acc1[mf][nf][r] + bv, 0.f);
                int byte = row * 512 + ((col * 2) ^ ((row & 7) << 4));
                *(short*)(Tlds + byte) = f2bf(tv);
            }
        }
    }
    __syncthreads();

    // GEMM2: wave w -> rows [w*16, w*16+16), cols 0..63, K = 256
    f32x4 acc2[4];
#pragma unroll
    for (int nf = 0; nf < 4; ++nf)
#pragma unroll
        for (int r = 0; r < 4; ++r) acc2[nf][r] = 0.f;

#pragma unroll
    for (int ks = 0; ks < 8; ++ks) {
        int row = w * 16 + li;
        int kb = (ks * 32 + lg * 8) * 2;
        bf16x8 at = *(const bf16x8*)(Tlds + row * 512 + (kb ^ ((row & 7) << 4)));
#pragma unroll
        for (int nf = 0; nf < 4; ++nf) {
            bf16x8 bw = *(const bf16x8*)(W2T + (size_t)(nf * 16 + li) * HID + ks * 32 + lg * 8);
            acc2[nf] = __builtin_amdgcn_mfma_f32_16x16x32_bf16(at, bw, acc2[nf], 0, 0, 0);
        }
    }

    // epilogue
#pragma unroll
    for (int r = 0; r < 4; ++r) {
        int row = r0 + w * 16 + lg * 4 + r;
        if (row < NN) {
            const float dv = dis[row];
#pragma unroll
            for (int nf = 0; nf < 4; ++nf) {
                float hv = acc2[nf][r] + b2[nf * 16 + li];
                size_t o = (size_t)row * CLS + nf * 16 + li;
                hb[o] = __float2bfloat16(hv);
                y0[o] = __float2bfloat16(hv * dv);
            }
        }
    }
}

// ---------------- propagation on y = z*dis (bf16) ----------------
// node is wave-uniform: rowptr/csrc hoisted to SGPR (s_load), gathers use
// SGPR base + lane*2 voffset. 8-wide unroll for memory-level parallelism.
template <int LAST>
__global__ __launch_bounds__(256) void prop_kernel(const __hip_bfloat16* __restrict__ yin,
                                                   const __hip_bfloat16* __restrict__ hb,
                                                   const float* __restrict__ dis,
                                                   const int* __restrict__ rowptr,
                                                   const int* __restrict__ csrc,
                                                   __hip_bfloat16* __restrict__ yout,
                                                   float* __restrict__ zout) {
    const int node = (blockIdx.x * 256 + threadIdx.x) >> 6;
    const int lane = threadIdx.x & 63;

    int p = __builtin_amdgcn_readfirstlane(rowptr[node]);
    const int e = __builtin_amdgcn_readfirstlane(rowptr[node + 1]);

    float acc = bf2f(yin[(size_t)node * CLS + lane]);  // self loop

    for (; p + 7 < e; p += 8) {
        int s0 = csrc[p + 0], s1 = csrc[p + 1], s2 = csrc[p + 2], s3 = csrc[p + 3];
        int s4 = csrc[p + 4], s5 = csrc[p + 5], s6 = csrc[p + 6], s7 = csrc[p + 7];
        float v0 = bf2f(yin[(size_t)s0 * CLS + lane]);
        float v1 = bf2f(yin[(size_t)s1 * CLS + lane]);
        float v2 = bf2f(yin[(size_t)s2 * CLS + lane]);
        float v3 = bf2f(yin[(size_t)s3 * CLS + lane]);
        float v4 = bf2f(yin[(size_t)s4 * CLS + lane]);
        float v5 = bf2f(yin[(size_t)s5 * CLS + lane]);
        float v6 = bf2f(yin[(size_t)s6 * CLS + lane]);
        float v7 = bf2f(yin[(size_t)s7 * CLS + lane]);
        acc += ((v0 + v1) + (v2 + v3)) + ((v4 + v5) + (v6 + v7));
    }
    for (; p < e; ++p)
        acc += bf2f(yin[(size_t)csrc[p] * CLS + lane]);

    const float din = dis[node];
    const float z = 0.9f * din * acc + 0.1f * bf2f(hb[(size_t)node * CLS + lane]);

    if (LAST) {
        float m = z;
#pragma unroll
        for (int o = 32; o; o >>= 1) m = fmaxf(m, __shfl_xor(m, o));
        float ev = __expf(z - m);
        float s = ev;
#pragma unroll
        for (int o = 32; o; o >>= 1) s += __shfl_xor(s, o);
        zout[(size_t)node * CLS + lane] = z - m - __logf(s);
    } else {
        yout[(size_t)node * CLS + lane] = __float2bfloat16(z * din);
    }
}

extern "C" void kernel_launch(void* const* d_in, const int* in_sizes, int n_in,
                              void* d_out, int out_size, void* d_ws, size_t ws_size,
                              hipStream_t stream) {
    const float* x  = (const float*)d_in[0];
    const int*   ei = (const int*)d_in[1];
    const float* W1 = (const float*)d_in[2];
    const float* b1 = (const float*)d_in[3];
    const float* W2 = (const float*)d_in[4];
    const float* b2 = (const float*)d_in[5];
    float* out = (float*)d_out;

    const int* esrc = ei;
    const int* edst = ei + EE;

    char* w = (char*)d_ws;
    auto alloc = [&](size_t bytes) {
        char* p = w;
        w += (bytes + 255) & ~(size_t)255;
        return p;
    };
    __hip_bfloat16* hb  = (__hip_bfloat16*)alloc((size_t)NN * CLS * 2);
    __hip_bfloat16* y0  = (__hip_bfloat16*)alloc((size_t)NN * CLS * 2);
    __hip_bfloat16* y1  = (__hip_bfloat16*)alloc((size_t)NN * CLS * 2);
    __hip_bfloat16* W1T = (__hip_bfloat16*)alloc((size_t)HID * FIN * 2);
    __hip_bfloat16* W2T = (__hip_bfloat16*)alloc((size_t)CLS * HID * 2);
    float* dis   = (float*)alloc((size_t)NN * 4);
    int* degcnt  = (int*)alloc((size_t)NN * 4);
    int* tmp     = (int*)alloc((size_t)NN * 4);
    int* rowptr  = (int*)alloc((size_t)(NN + 1) * 4);
    int* cursor  = (int*)alloc((size_t)NN * 4);
    int* csrc    = (int*)alloc((size_t)EE * 4);
    int* bsum    = (int*)alloc(128 * 4);
    int* boff    = (int*)alloc(128 * 4);

    const int nbN = (NN + 255) / 256;
    const int nbE = (EE + 255) / 256;
    const int nscan = (NN + 1023) / 1024;

    zero_kernel<<<nbN, 256, 0, stream>>>(degcnt, cursor);
    count_kernel<<<nbE, 256, 0, stream>>>(edst, degcnt);
    scan1_kernel<<<nscan, 1024, 0, stream>>>(degcnt, tmp, bsum);
    scan2_kernel<<<1, 64, 0, stream>>>(bsum, boff, nscan);
    finalize_kernel<<<nbN, 256, 0, stream>>>(tmp, boff, degcnt, rowptr, dis);
    fill_kernel<<<nbE, 256, 0, stream>>>(esrc, edst, rowptr, cursor, csrc);

    w1t_kernel<<<(HID * FIN) / 256, 256, 0, stream>>>(W1, W1T);
    w2t_kernel<<<(CLS * HID) / 256, 256, 0, stream>>>(W2, W2T);

    mlp_kernel<<<(NN + 63) / 64, 256, 0, stream>>>(x, W1T, b1, W2T, b2, dis, hb, y0);

    const __hip_bfloat16* yin = y0;
    __hip_bfloat16* yout = y1;
    for (int s = 0; s < KST - 1; ++s) {
        prop_kernel<0><<<(NN * CLS) / 256, 256, 0, stream>>>(yin, hb, dis, rowptr, csrc, yout, nullptr);
        const __hip_bfloat16* t2 = yin;
        yin = yout;
        yout = (__hip_bfloat16*)t2;
    }
    prop_kernel<1><<<(NN * CLS) / 256, 256, 0, stream>>>(yin, hb, dis, rowptr, csrc, nullptr, out);
}

// Round 4
// 1628.518 us; speedup vs baseline: 2.8676x; 1.1050x over previous
//
#include <hip/hip_runtime.h>
#include <hip/hip_bf16.h>
#include <math.h>

#define NN 100000
#define EE 3200000
#define FIN 512
#define HID 256
#define CLS 64
#define KST 20

typedef __attribute__((ext_vector_type(8))) short bf16x8;
typedef __attribute__((ext_vector_type(4))) float f32x4;

__device__ __forceinline__ short f2bf(float f) {
    union { __hip_bfloat16 b; short s; } u;
    u.b = __float2bfloat16(f);
    return u.s;
}
__device__ __forceinline__ float bf2f(__hip_bfloat16 b) { return __bfloat162float(b); }

// ---------------- CSR build ----------------

__global__ void zero_kernel(int* __restrict__ degcnt, int* __restrict__ cursor) {
    int i = blockIdx.x * 256 + threadIdx.x;
    if (i < NN) { degcnt[i] = 0; cursor[i] = 0; }
}

__global__ void count_kernel(const int* __restrict__ edst, int* __restrict__ degcnt) {
    int e = blockIdx.x * 256 + threadIdx.x;
    if (e < EE) atomicAdd(&degcnt[edst[e]], 1);
}

__global__ __launch_bounds__(1024) void scan1_kernel(const int* __restrict__ degcnt,
                                                     int* __restrict__ tmp,
                                                     int* __restrict__ bsum) {
    __shared__ int s[1024];
    int t = threadIdx.x;
    int i = blockIdx.x * 1024 + t;
    int v = (i < NN) ? degcnt[i] : 0;
    s[t] = v;
    __syncthreads();
    for (int off = 1; off < 1024; off <<= 1) {
        int xv = (t >= off) ? s[t - off] : 0;
        __syncthreads();
        s[t] += xv;
        __syncthreads();
    }
    if (i < NN) tmp[i] = s[t] - v;
    if (t == 1023) bsum[blockIdx.x] = s[1023];
}

__global__ void scan2_kernel(const int* __restrict__ bsum, int* __restrict__ boff, int nb) {
    if (blockIdx.x == 0 && threadIdx.x == 0) {
        int run = 0;
        for (int b = 0; b < nb; ++b) { boff[b] = run; run += bsum[b]; }
    }
}

__global__ void finalize_kernel(const int* __restrict__ tmp, const int* __restrict__ boff,
                                const int* __restrict__ degcnt,
                                int* __restrict__ rowptr, float* __restrict__ dis) {
    int i = blockIdx.x * 256 + threadIdx.x;
    if (i < NN) {
        rowptr[i] = tmp[i] + boff[i >> 10];
        dis[i] = rsqrtf((float)(degcnt[i] + 1));
        if (i == 0) rowptr[NN] = EE;
    }
}

__global__ void fill_kernel(const int* __restrict__ esrc, const int* __restrict__ edst,
                            const int* __restrict__ rowptr, int* __restrict__ cursor,
                            int* __restrict__ csrc) {
    int e = blockIdx.x * 256 + threadIdx.x;
    if (e < EE) {
        int d = edst[e];
        int pos = atomicAdd(&cursor[d], 1);
        csrc[rowptr[d] + pos] = esrc[e];
    }
}

// ---------------- weight prep: fragment-tiled bf16 ----------------
// Layout: tile (coltile, ktile) of 16 cols x 32 k = 512 elems (1 KB).
// Within tile: elem = (c&15)*32 + ((k>>3)&3)*8 + (k&7). A wave's fragment
// load (lane lg*16+li reads 16B at li*32+lg*8) is one coalesced 1KB request.

__global__ void w1t_kernel(const float* __restrict__ W1, __hip_bfloat16* __restrict__ W1Tt) {
    const int c = threadIdx.x;       // 0..255
    const int kg = blockIdx.x;       // 0..63 (k-group of 8)
    bf16x8 o;
#pragma unroll
    for (int j = 0; j < 8; ++j) o[j] = f2bf(W1[(size_t)(kg * 8 + j) * HID + c]);
    size_t dst = ((size_t)((c >> 4) * 16 + (kg >> 2))) * 512 + (c & 15) * 32 + (kg & 3) * 8;
    *(bf16x8*)((short*)W1Tt + dst) = o;
}

__global__ void w2t_kernel(const float* __restrict__ W2, __hip_bfloat16* __restrict__ W2Tt) {
    const int c = threadIdx.x;       // 0..63
    const int kg = blockIdx.x;       // 0..31
    bf16x8 o;
#pragma unroll
    for (int j = 0; j < 8; ++j) o[j] = f2bf(W2[(size_t)(kg * 8 + j) * CLS + c]);
    size_t dst = ((size_t)((c >> 4) * 8 + (kg >> 2))) * 512 + (c & 15) * 32 + (kg & 3) * 8;
    *(bf16x8*)((short*)W2Tt + dst) = o;
}

// ---------------- MFMA MLP (barrier-free GEMM1) ----------------
// Block = 4 waves, 64 rows. A-fragments read DIRECTLY from global x (f32,
// cvt in-register); B from fragment-tiled W1Tt (1KB coalesced loads). No LDS
// staging, no barriers in GEMM1 -> compiler software-pipelines the stream.
// T exchanged via swizzled LDS; GEMM2 M-split across waves.
__device__ __forceinline__ bf16x8 load_a8(const float* p) {
    const float4 f0 = *(const float4*)p;
    const float4 f1 = *(const float4*)(p + 4);
    bf16x8 r;
    r[0] = f2bf(f0.x); r[1] = f2bf(f0.y); r[2] = f2bf(f0.z); r[3] = f2bf(f0.w);
    r[4] = f2bf(f1.x); r[5] = f2bf(f1.y); r[6] = f2bf(f1.z); r[7] = f2bf(f1.w);
    return r;
}

__global__ __launch_bounds__(256, 2) void mlp_kernel(const float* __restrict__ x,
                                                     const __hip_bfloat16* __restrict__ W1Tt,
                                                     const float* __restrict__ b1,
                                                     const __hip_bfloat16* __restrict__ W2Tt,
                                                     const float* __restrict__ b2,
                                                     const float* __restrict__ dis,
                                                     __hip_bfloat16* __restrict__ hb,
                                                     __hip_bfloat16* __restrict__ y0) {
    __shared__ __align__(16) char Tlds[64 * 512];   // 64 rows x 256 cols bf16, swizzled

    const int t = threadIdx.x;
    const int w = t >> 6;
    const int lane = t & 63;
    const int lg = lane >> 4;
    const int li = lane & 15;
    const int loff = li * 32 + lg * 8;              // fragment offset within 1KB tile
    const int r0 = blockIdx.x * 64;

    const short* W1s = (const short*)W1Tt;
    const short* W2s = (const short*)W2Tt;

    // A row pointers (clamped)
    const float* xrow[4];
#pragma unroll
    for (int mf = 0; mf < 4; ++mf) {
        int r = r0 + mf * 16 + li;
        xrow[mf] = x + (size_t)((r < NN) ? r : (NN - 1)) * FIN;
    }

    f32x4 acc1[4][4];
#pragma unroll
    for (int mf = 0; mf < 4; ++mf)
#pragma unroll
        for (int nf = 0; nf < 4; ++nf)
#pragma unroll
            for (int r = 0; r < 4; ++r) acc1[mf][nf][r] = 0.f;

#pragma unroll
    for (int kt = 0; kt < 16; ++kt) {
        bf16x8 bfw[4];
#pragma unroll
        for (int nf = 0; nf < 4; ++nf)
            bfw[nf] = *(const bf16x8*)(W1s + ((size_t)((w * 4 + nf) * 16 + kt)) * 512 + loff);
#pragma unroll
        for (int mf = 0; mf < 4; ++mf) {
            bf16x8 af = load_a8(xrow[mf] + kt * 32 + lg * 8);
#pragma unroll
            for (int nf = 0; nf < 4; ++nf)
                acc1[mf][nf] = __builtin_amdgcn_mfma_f32_16x16x32_bf16(
                    af, bfw[nf], acc1[mf][nf], 0, 0, 0);
        }
    }

    // T = relu(acc1 + b1) -> swizzled LDS (wave w owns cols w*64..w*64+63)
#pragma unroll
    for (int nf = 0; nf < 4; ++nf) {
        const float bv = b1[w * 64 + nf * 16 + li];
        const int col = w * 64 + nf * 16 + li;
#pragma unroll
        for (int mf = 0; mf < 4; ++mf) {
#pragma unroll
            for (int r = 0; r < 4; ++r) {
                int row = mf * 16 + lg * 4 + r;
                float tv = fmaxf(acc1[mf][nf][r] + bv, 0.f);
                int byte = row * 512 + ((col * 2) ^ ((row & 7) << 4));
                *(short*)(Tlds + byte) = f2bf(tv);
            }
        }
    }
    __syncthreads();

    // GEMM2: wave w -> rows [w*16, w*16+16), K = 256
    f32x4 acc2[4];
#pragma unroll
    for (int nf = 0; nf < 4; ++nf)
#pragma unroll
        for (int r = 0; r < 4; ++r) acc2[nf][r] = 0.f;

#pragma unroll
    for (int kt2 = 0; kt2 < 8; ++kt2) {
        int row = w * 16 + li;
        int kb = (kt2 * 32 + lg * 8) * 2;
        bf16x8 at = *(const bf16x8*)(Tlds + row * 512 + (kb ^ ((row & 7) << 4)));
#pragma unroll
        for (int nf = 0; nf < 4; ++nf) {
            bf16x8 bw = *(const bf16x8*)(W2s + ((size_t)(nf * 8 + kt2)) * 512 + loff);
            acc2[nf] = __builtin_amdgcn_mfma_f32_16x16x32_bf16(at, bw, acc2[nf], 0, 0, 0);
        }
    }

    // epilogue
#pragma unroll
    for (int r = 0; r < 4; ++r) {
        int row = r0 + w * 16 + lg * 4 + r;
        if (row < NN) {
            const float dv = dis[row];
#pragma unroll
            for (int nf = 0; nf < 4; ++nf) {
                float hv = acc2[nf][r] + b2[nf * 16 + li];
                size_t o = (size_t)row * CLS + nf * 16 + li;
                hb[o] = __float2bfloat16(hv);
                y0[o] = __float2bfloat16(hv * dv);
            }
        }
    }
}

// ---------------- propagation on y = z*dis (bf16) ----------------
// 16 outstanding gathers per batch; csrc fetched as uniform int4 (s_load);
// 4 independent accumulators break the add chain.
template <int LAST>
__global__ __launch_bounds__(256) void prop_kernel(const __hip_bfloat16* __restrict__ yin,
                                                   const __hip_bfloat16* __restrict__ hb,
                                                   const float* __restrict__ dis,
                                                   const int* __restrict__ rowptr,
                                                   const int* __restrict__ csrc,
                                                   __hip_bfloat16* __restrict__ yout,
                                                   float* __restrict__ zout) {
    const int node = blockIdx.x * 4 + (threadIdx.x >> 6);
    const int lane = threadIdx.x & 63;

    int p = __builtin_amdgcn_readfirstlane(rowptr[node]);
    const int e = __builtin_amdgcn_readfirstlane(rowptr[node + 1]);

    const __hip_bfloat16* Y = yin + lane;

    float a0 = bf2f(Y[(size_t)node << 6]);   // self loop
    float a1 = 0.f, a2 = 0.f, a3 = 0.f;

    for (; p + 16 <= e; p += 16) {
        const int4 i0 = *(const int4*)(csrc + p);
        const int4 i1 = *(const int4*)(csrc + p + 4);
        const int4 i2 = *(const int4*)(csrc + p + 8);
        const int4 i3 = *(const int4*)(csrc + p + 12);
        float v0 = bf2f(Y[(size_t)i0.x << 6]);
        float v1 = bf2f(Y[(size_t)i0.y << 6]);
        float v2 = bf2f(Y[(size_t)i0.z << 6]);
        float v3 = bf2f(Y[(size_t)i0.w << 6]);
        float v4 = bf2f(Y[(size_t)i1.x << 6]);
        float v5 = bf2f(Y[(size_t)i1.y << 6]);
        float v6 = bf2f(Y[(size_t)i1.z << 6]);
        float v7 = bf2f(Y[(size_t)i1.w << 6]);
        float v8 = bf2f(Y[(size_t)i2.x << 6]);
        float v9 = bf2f(Y[(size_t)i2.y << 6]);
        float va = bf2f(Y[(size_t)i2.z << 6]);
        float vb = bf2f(Y[(size_t)i2.w << 6]);
        float vc = bf2f(Y[(size_t)i3.x << 6]);
        float vd = bf2f(Y[(size_t)i3.y << 6]);
        float ve = bf2f(Y[(size_t)i3.z << 6]);
        float vf = bf2f(Y[(size_t)i3.w << 6]);
        a0 += (v0 + v1) + (v2 + v3);
        a1 += (v4 + v5) + (v6 + v7);
        a2 += (v8 + v9) + (va + vb);
        a3 += (vc + vd) + (ve + vf);
    }
    for (; p + 4 <= e; p += 4) {
        const int4 i0 = *(const int4*)(csrc + p);
        float v0 = bf2f(Y[(size_t)i0.x << 6]);
        float v1 = bf2f(Y[(size_t)i0.y << 6]);
        float v2 = bf2f(Y[(size_t)i0.z << 6]);
        float v3 = bf2f(Y[(size_t)i0.w << 6]);
        a1 += (v0 + v1) + (v2 + v3);
    }
    for (; p < e; ++p)
        a2 += bf2f(Y[(size_t)csrc[p] << 6]);

    const float acc = (a0 + a1) + (a2 + a3);
    const float din = dis[node];
    const float z = 0.9f * din * acc + 0.1f * bf2f(hb[((size_t)node << 6) + lane]);

    if (LAST) {
        float m = z;
#pragma unroll
        for (int o = 32; o; o >>= 1) m = fmaxf(m, __shfl_xor(m, o));
        float ev = __expf(z - m);
        float s = ev;
#pragma unroll
        for (int o = 32; o; o >>= 1) s += __shfl_xor(s, o);
        zout[((size_t)node << 6) + lane] = z - m - __logf(s);
    } else {
        yout[((size_t)node << 6) + lane] = __float2bfloat16(z * din);
    }
}

extern "C" void kernel_launch(void* const* d_in, const int* in_sizes, int n_in,
                              void* d_out, int out_size, void* d_ws, size_t ws_size,
                              hipStream_t stream) {
    const float* x  = (const float*)d_in[0];
    const int*   ei = (const int*)d_in[1];
    const float* W1 = (const float*)d_in[2];
    const float* b1 = (const float*)d_in[3];
    const float* W2 = (const float*)d_in[4];
    const float* b2 = (const float*)d_in[5];
    float* out = (float*)d_out;

    const int* esrc = ei;
    const int* edst = ei + EE;

    char* w = (char*)d_ws;
    auto alloc = [&](size_t bytes) {
        char* p = w;
        w += (bytes + 255) & ~(size_t)255;
        return p;
    };
    __hip_bfloat16* hb   = (__hip_bfloat16*)alloc((size_t)NN * CLS * 2);
    __hip_bfloat16* y0   = (__hip_bfloat16*)alloc((size_t)NN * CLS * 2);
    __hip_bfloat16* y1   = (__hip_bfloat16*)alloc((size_t)NN * CLS * 2);
    __hip_bfloat16* W1Tt = (__hip_bfloat16*)alloc((size_t)HID * FIN * 2);
    __hip_bfloat16* W2Tt = (__hip_bfloat16*)alloc((size_t)CLS * HID * 2);
    float* dis   = (float*)alloc((size_t)NN * 4);
    int* degcnt  = (int*)alloc((size_t)NN * 4);
    int* tmp     = (int*)alloc((size_t)NN * 4);
    int* rowptr  = (int*)alloc((size_t)(NN + 1) * 4);
    int* cursor  = (int*)alloc((size_t)NN * 4);
    int* csrc    = (int*)alloc((size_t)EE * 4);
    int* bsum    = (int*)alloc(128 * 4);
    int* boff    = (int*)alloc(128 * 4);

    const int nbN = (NN + 255) / 256;
    const int nbE = (EE + 255) / 256;
    const int nscan = (NN + 1023) / 1024;

    zero_kernel<<<nbN, 256, 0, stream>>>(degcnt, cursor);
    count_kernel<<<nbE, 256, 0, stream>>>(edst, degcnt);
    scan1_kernel<<<nscan, 1024, 0, stream>>>(degcnt, tmp, bsum);
    scan2_kernel<<<1, 64, 0, stream>>>(bsum, boff, nscan);
    finalize_kernel<<<nbN, 256, 0, stream>>>(tmp, boff, degcnt, rowptr, dis);
    fill_kernel<<<nbE, 256, 0, stream>>>(esrc, edst, rowptr, cursor, csrc);

    w1t_kernel<<<FIN / 8, HID, 0, stream>>>(W1, W1Tt);
    w2t_kernel<<<HID / 8, CLS, 0, stream>>>(W2, W2Tt);

    mlp_kernel<<<(NN + 63) / 64, 256, 0, stream>>>(x, W1Tt, b1, W2Tt, b2, dis, hb, y0);

    const __hip_bfloat16* yin = y0;
    __hip_bfloat16* yout = y1;
    for (int s = 0; s < KST - 1; ++s) {
        prop_kernel<0><<<NN / 4, 256, 0, stream>>>(yin, hb, dis, rowptr, csrc, yout, nullptr);
        const __hip_bfloat16* t2 = yin;
        yin = yout;
        yout = (__hip_bfloat16*)t2;
    }
    prop_kernel<1><<<NN / 4, 256, 0, stream>>>(yin, hb, dis, rowptr, csrc, nullptr, out);
}